// Round 6
// baseline (583.651 us; speedup 1.0000x reference)
//
#include <hip/hip_runtime.h>

#define DF 128
#define MT 64          // rows per block (edge)
#define MTS 32         // rows per block (pq/node)
#define LNEPS 1e-5f
#define NATOMS 20000

typedef __attribute__((ext_vector_type(8))) short short8;
typedef __attribute__((ext_vector_type(4))) short short4v;
typedef __attribute__((ext_vector_type(4))) float float4v;

// ---- module-global scratch ----
#define EW0H 0
#define EW0L (EW0H + 384*128)
#define EW1H (EW0L + 384*128)
#define EW1L (EW1H + 128*128)
#define EW2H (EW1L + 128*128)
#define EW2L (EW2H + 128*128)
#define NW0H (EW2L + 128*128)
#define NW0L (NW0H + 128*128)
#define NW1H (NW0L + 128*128)
#define NW1L (NW1H + 128*128)
#define NW2H (NW1L + 128*128)
#define NW2L (NW2H + 128*128)
#define WTOT (NW2L + 128*128)   // 262144 shorts = 512 KB

__device__ short g_w[WTOT];
__device__ float g_nodein[NATOMS * DF];   // 10.24 MB
__device__ float g_P[NATOMS * DF];        // x @ W0a (recv part)
__device__ float g_Q[NATOMS * DF];        // x @ W0b (send part)
__device__ float g_sgs[8], g_sbs[8];      // per-16-chunk sum(gamma), sum(beta) for edge LN

__device__ __forceinline__ short f2bf(float f) {
    union { float f; unsigned u; } v; v.f = f;
    unsigned r = v.u + 0x7FFFu + ((v.u >> 16) & 1u);  // RNE
    return (short)(r >> 16);
}
__device__ __forceinline__ float bf2f(short s) {
    union { unsigned u; float f; } v; v.u = ((unsigned)(unsigned short)s) << 16;
    return v.f;
}
struct B2 { short hi, lo; };
// exact-RNE split (weight convert only)
__device__ __forceinline__ B2 f2b2(float v) {
    B2 r;
    r.hi = f2bf(v);
    r.lo = f2bf(v - bf2f(r.hi));
    return r;
}
// fast split: half-up rounding, ~6 VALU
__device__ __forceinline__ B2 f2b2_fast(float v) {
    union { float f; unsigned u; } a; a.f = v;
    const unsigned hu = (a.u + 0x8000u) & 0xFFFF0000u;
    union { unsigned u; float f; } h; h.u = hu;
    const float rr = v - h.f;
    union { float f; unsigned u; } b; b.f = rr;
    B2 o;
    o.hi = (short)(hu >> 16);
    o.lo = (short)((b.u + 0x8000u) >> 16);
    return o;
}

// ---------------- weight convert: bf16 hi/lo, transposed [out][in] ----------------
struct WConvArgs {
    const float* W[6];
    int din[6];
    const float* g;    // edge LN gamma
    const float* bt;   // edge LN beta
};

__global__ void wconv_all(WConvArgs a) {
    const int b = blockIdx.x;
    if (b == 512) {   // per-chunk gamma/beta sums for the edge LN epilogue
        if (threadIdx.x < 8) {
            float sg = 0.f, sb = 0.f;
#pragma unroll
            for (int j = 0; j < 16; ++j) {
                sg += a.g[threadIdx.x * 16 + j];
                sb += a.bt[threadIdx.x * 16 + j];
            }
            g_sgs[threadIdx.x] = sg;
            g_sbs[threadIdx.x] = sb;
        }
        return;
    }
    const int baseh[6] = {EW0H, EW1H, EW2H, NW0H, NW1H, NW2H};
    const int dlo[6]   = {384*128, 128*128, 128*128, 128*128, 128*128, 128*128};
    int m, idx;
    if (b < 192) { m = 0; idx = b * 256 + threadIdx.x; }                 // eW0: 384*128
    else { m = 1 + (b - 192) / 64; idx = ((b - 192) % 64) * 256 + threadIdx.x; }
    const int din = a.din[m];
    const int o = idx / din, i = idx - o * din;
    const float w = a.W[m][(size_t)i * DF + o];
    B2 r = f2b2(w);
    g_w[baseh[m] + idx] = r.hi;
    g_w[baseh[m] + dlo[m] + idx] = r.lo;
}

// ---------------- MTWx16-row x 64-col per-wave MFMA tile, 3-pass bf16 hi/lo ----------------
template<int MTW>
__device__ __forceinline__ void mm_tile_t(float4v (&acc)[MTW][4],
                                          const short (*hi)[136], const short (*lo)[136],
                                          const short* __restrict__ Whi,
                                          const short* __restrict__ Wlo,
                                          int wstride, int kbase,
                                          int m0, int n0, int quad, int lq)
{
#pragma unroll
    for (int ks = 0; ks < 4; ++ks) {
        const int k0 = ks * 32 + quad * 8;
        short8 ah[MTW], al[MTW], bh[4], bl[4];
#pragma unroll
        for (int mt = 0; mt < MTW; ++mt) {
            const int r = m0 + mt * 16 + lq;
            ah[mt] = *(const short8*)&hi[r][k0];
            al[mt] = *(const short8*)&lo[r][k0];
        }
#pragma unroll
        for (int nt = 0; nt < 4; ++nt) {
            const size_t off = (size_t)(n0 + nt * 16 + lq) * wstride + kbase + k0;
            bh[nt] = *(const short8*)(Whi + off);
            bl[nt] = *(const short8*)(Wlo + off);
        }
#pragma unroll
        for (int mt = 0; mt < MTW; ++mt)
#pragma unroll
            for (int nt = 0; nt < 4; ++nt) {
                acc[mt][nt] = __builtin_amdgcn_mfma_f32_16x16x32_bf16(ah[mt], bh[nt], acc[mt][nt], 0, 0, 0);
                acc[mt][nt] = __builtin_amdgcn_mfma_f32_16x16x32_bf16(al[mt], bh[nt], acc[mt][nt], 0, 0, 0);
                acc[mt][nt] = __builtin_amdgcn_mfma_f32_16x16x32_bf16(ah[mt], bl[nt], acc[mt][nt], 0, 0, 0);
            }
    }
}

template<int MTW>
__device__ __forceinline__ void relu_store_t(float4v (&acc)[MTW][4],
                                             short (*hi)[136], short (*lo)[136],
                                             const float* __restrict__ bias,
                                             int m0, int n0, int quad, int lq)
{
#pragma unroll
    for (int nt = 0; nt < 4; ++nt) {
        const float bb = bias[n0 + nt * 16 + lq];
#pragma unroll
        for (int mt = 0; mt < MTW; ++mt)
#pragma unroll
            for (int i = 0; i < 4; ++i) {
                const float v = fmaxf(acc[mt][nt][i] + bb, 0.f);
                const int r = m0 + mt * 16 + quad * 4 + i;
                const int c = n0 + nt * 16 + lq;
                B2 s = f2b2_fast(v);
                hi[r][c] = s.hi;
                lo[r][c] = s.lo;
                acc[mt][nt][i] = 0.f;
            }
    }
}

// ---------------- P/Q precompute: P = x@W0a, Q = x@W0b  (MT=32 for CU fill) ----------------
__launch_bounds__(256, 4)
__global__ void pq_kernel(const float* __restrict__ x, int N)
{
    __shared__ short s_hi[MTS][136];
    __shared__ short s_lo[MTS][136];

    const int tid = threadIdx.x;
    const int wave = tid >> 6, lane = tid & 63;
    const int quad = lane >> 4, lq = lane & 15;
    const int m0 = (wave & 1) * 16, n0 = (wave >> 1) * 64;
    const int a0 = blockIdx.x * MTS;

    const short* W0h = &g_w[EW0H]; const short* W0l = &g_w[EW0L];

#pragma unroll
    for (int it = 0; it < 4; ++it) {
        const int flat = it * 1024 + tid * 4;
        const int r = flat >> 7, f = flat & 127;
        float4 v = {0.f, 0.f, 0.f, 0.f};
        if (a0 + r < N) v = *(const float4*)(x + (size_t)(a0 + r) * DF + f);
        short4v hv, lv;
        B2 t0 = f2b2_fast(v.x); hv[0] = t0.hi; lv[0] = t0.lo;
        B2 t1 = f2b2_fast(v.y); hv[1] = t1.hi; lv[1] = t1.lo;
        B2 t2 = f2b2_fast(v.z); hv[2] = t2.hi; lv[2] = t2.lo;
        B2 t3 = f2b2_fast(v.w); hv[3] = t3.hi; lv[3] = t3.lo;
        *(short4v*)&s_hi[r][f] = hv;
        *(short4v*)&s_lo[r][f] = lv;
    }
    __syncthreads();

    float4v acc[1][4] = {};
    // P: K-slice 0..127 of eW0
    mm_tile_t<1>(acc, s_hi, s_lo, W0h, W0l, 384, 0, m0, n0, quad, lq);
#pragma unroll
    for (int i = 0; i < 4; ++i) {
        const int a = a0 + m0 + quad * 4 + i;
        if (a < N)
#pragma unroll
            for (int nt = 0; nt < 4; ++nt)
                g_P[(size_t)a * DF + n0 + nt * 16 + lq] = acc[0][nt][i];
#pragma unroll
        for (int nt = 0; nt < 4; ++nt) acc[0][nt][i] = 0.f;
    }
    // Q: K-slice 128..255 (staging unchanged, no barrier needed)
    mm_tile_t<1>(acc, s_hi, s_lo, W0h, W0l, 384, 128, m0, n0, quad, lq);
#pragma unroll
    for (int i = 0; i < 4; ++i) {
        const int a = a0 + m0 + quad * 4 + i;
        if (a < N)
#pragma unroll
            for (int nt = 0; nt < 4; ++nt)
                g_Q[(size_t)a * DF + n0 + nt * 16 + lq] = acc[0][nt][i];
    }
}

// ---------------- fused edge MLP + LN + chunk-sum ----------------
__launch_bounds__(256, 4)
__global__ void edge_kernel(
    const float* __restrict__ edge_attr,
    const int* __restrict__ recv, const int* __restrict__ send,
    const float* __restrict__ b0, const float* __restrict__ b1, const float* __restrict__ b2,
    const float* __restrict__ gamma, const float* __restrict__ beta,
    int E)
{
    __shared__ short s_hi[MT][136];
    __shared__ short s_lo[MT][136];
    __shared__ float spS[MT][2], spSS[MT][2];   // per-row sum / sumsq (by n0-half)
    __shared__ float cs[MT][8];                 // per-row per-chunk gamma-dot

    const int tid = threadIdx.x;
    const int wave = tid >> 6, lane = tid & 63;
    const int quad = lane >> 4, lq = lane & 15;
    const int m0 = (wave >> 1) * 32, n0 = (wave & 1) * 64;
    const int e0 = blockIdx.x * MT;

    const short* W0h = &g_w[EW0H]; const short* W0l = &g_w[EW0L];
    const short* W1h = &g_w[EW1H]; const short* W1l = &g_w[EW1L];
    const short* W2h = &g_w[EW2H]; const short* W2l = &g_w[EW2L];

    // ---- phase A0: index loads FIRST (head of the longest chain: idx -> gather) ----
    int rr[8], sr[8];
#pragma unroll
    for (int mt = 0; mt < 2; ++mt)
#pragma unroll
        for (int i = 0; i < 4; ++i) {
            const int r = m0 + mt * 16 + quad * 4 + i;
            const int e = e0 + r;
            rr[mt * 4 + i] = (e < E) ? recv[e] : 0;
            sr[mt * 4 + i] = (e < E) ? send[e] : 0;
        }

    // ---- phase A1: stream edge_attr tile into registers (flies under idx latency) ----
    const float* easrc = edge_attr + (size_t)e0 * DF;
    float4 eav[8];
#pragma unroll
    for (int it = 0; it < 8; ++it) {
        const int flat = it * 1024 + tid * 4;
        float4 z = {0.f, 0.f, 0.f, 0.f};
        eav[it] = (e0 + (flat >> 7) < E) ? *(const float4*)(easrc + flat) : z;
    }

    // ---- phase A2: per-lane PQ gather — each lane loads exactly the 32 P + 32 Q
    // dwords its acc fragments need (64 independent dword loads, no LDS round trip) ----
    float pqp[2][4][4], pqq[2][4][4];
#pragma unroll
    for (int mt = 0; mt < 2; ++mt)
#pragma unroll
        for (int i = 0; i < 4; ++i) {
            const float* Pr = g_P + (size_t)rr[mt * 4 + i] * DF + n0 + lq;
            const float* Qr = g_Q + (size_t)sr[mt * 4 + i] * DF + n0 + lq;
#pragma unroll
            for (int nt = 0; nt < 4; ++nt) {
                pqp[mt][nt][i] = Pr[nt * 16];
                pqq[mt][nt][i] = Qr[nt * 16];
            }
        }

    // ---- phase C: edge_attr -> bf16 hi/lo staging (VALU work hides gather latency) ----
#pragma unroll
    for (int it = 0; it < 8; ++it) {
        const int flat = it * 1024 + tid * 4;
        const int rw = flat >> 7, c = flat & 127;
        short4v hv, lv;
        B2 t0 = f2b2_fast(eav[it].x); hv[0] = t0.hi; lv[0] = t0.lo;
        B2 t1 = f2b2_fast(eav[it].y); hv[1] = t1.hi; lv[1] = t1.lo;
        B2 t2 = f2b2_fast(eav[it].z); hv[2] = t2.hi; lv[2] = t2.lo;
        B2 t3 = f2b2_fast(eav[it].w); hv[3] = t3.hi; lv[3] = t3.lo;
        *(short4v*)&s_hi[rw][c] = hv;
        *(short4v*)&s_lo[rw][c] = lv;
    }
    __syncthreads();

    // acc starts as the P+Q contribution; mm0 accumulates ea @ W0c on top
    float4v acc[2][4];
#pragma unroll
    for (int mt = 0; mt < 2; ++mt)
#pragma unroll
        for (int nt = 0; nt < 4; ++nt) {
            float4v t;
#pragma unroll
            for (int i = 0; i < 4; ++i)
                t[i] = pqp[mt][nt][i] + pqq[mt][nt][i];
            acc[mt][nt] = t;
        }

    mm_tile_t<2>(acc, s_hi, s_lo, W0h, W0l, 384, 256, m0, n0, quad, lq);
    __syncthreads();
    relu_store_t<2>(acc, s_hi, s_lo, b0, m0, n0, quad, lq);
    __syncthreads();
    mm_tile_t<2>(acc, s_hi, s_lo, W1h, W1l, DF, 0, m0, n0, quad, lq);
    __syncthreads();
    relu_store_t<2>(acc, s_hi, s_lo, b1, m0, n0, quad, lq);
    __syncthreads();
    mm_tile_t<2>(acc, s_hi, s_lo, W2h, W2l, DF, 0, m0, n0, quad, lq);

    // ---- LN epilogue pass 1: register-level shuffle reductions ----
    float gl[4], bb[4];
#pragma unroll
    for (int nt = 0; nt < 4; ++nt) {
        gl[nt] = gamma[n0 + nt * 16 + lq];
        bb[nt] = b2[n0 + nt * 16 + lq];
    }
    const int half = n0 >> 6;
#pragma unroll
    for (int mt = 0; mt < 2; ++mt)
#pragma unroll
        for (int i = 0; i < 4; ++i) {
            float v[4], vs = 0.f, vss = 0.f;
#pragma unroll
            for (int nt = 0; nt < 4; ++nt) {
                v[nt] = acc[mt][nt][i] + bb[nt];
                vs += v[nt]; vss += v[nt] * v[nt];
            }
            vs  += __shfl_xor(vs, 1);  vs  += __shfl_xor(vs, 2);
            vs  += __shfl_xor(vs, 4);  vs  += __shfl_xor(vs, 8);
            vss += __shfl_xor(vss, 1); vss += __shfl_xor(vss, 2);
            vss += __shfl_xor(vss, 4); vss += __shfl_xor(vss, 8);
            float cd[4];
#pragma unroll
            for (int nt = 0; nt < 4; ++nt) {
                float c = v[nt] * gl[nt];
                c += __shfl_xor(c, 1); c += __shfl_xor(c, 2);
                c += __shfl_xor(c, 4); c += __shfl_xor(c, 8);
                cd[nt] = c;
            }
            if (lq == 0) {
                const int row = m0 + mt * 16 + quad * 4 + i;
                spS[row][half] = vs;
                spSS[row][half] = vss;
#pragma unroll
                for (int nt = 0; nt < 4; ++nt)
                    cs[row][(n0 >> 4) + nt] = cd[nt];
            }
        }
    __syncthreads();

    // ---- pass 2: finalize LN-transformed chunk sums, write node_in ----
    for (int cell = tid; cell < MT * 8; cell += 256) {
        const int rw = cell >> 3, c = cell & 7;
        const float mu  = (spS[rw][0] + spS[rw][1]) * (1.f / 128.f);
        const float var = (spSS[rw][0] + spSS[rw][1]) * (1.f / 128.f) - mu * mu;
        const float inv = rsqrtf(var + LNEPS);
        const int ee = e0 + rw;
        if (ee < E)
            g_nodein[(size_t)ee * 8 + c] = inv * (cs[rw][c] - mu * g_sgs[c]) + g_sbs[c];
    }
}

// ---------------- fused node MLP + LN: g_nodein -> d_out  (MT=32 for CU fill) ----------------
__launch_bounds__(256, 4)
__global__ void node_kernel(
    float* __restrict__ out,
    const float* __restrict__ b0, const float* __restrict__ b1, const float* __restrict__ b2,
    const float* __restrict__ gamma, const float* __restrict__ beta,
    int N)
{
    __shared__ short s_hi[MTS][136];
    __shared__ short s_lo[MTS][136];
    __shared__ float spS[MTS][2], spSS[MTS][2];

    const int tid = threadIdx.x;
    const int wave = tid >> 6, lane = tid & 63;
    const int quad = lane >> 4, lq = lane & 15;
    const int m0 = (wave & 1) * 16, n0 = (wave >> 1) * 64;
    const int a0 = blockIdx.x * MTS;

    const short* W0h = &g_w[NW0H]; const short* W0l = &g_w[NW0L];
    const short* W1h = &g_w[NW1H]; const short* W1l = &g_w[NW1L];
    const short* W2h = &g_w[NW2H]; const short* W2l = &g_w[NW2L];

    float4v acc[1][4] = {};

#pragma unroll
    for (int it = 0; it < 4; ++it) {
        const int flat = it * 1024 + tid * 4;
        const int r = flat >> 7, f = flat & 127;
        float4 v = {0.f, 0.f, 0.f, 0.f};
        if (a0 + r < N) v = *(const float4*)(g_nodein + (size_t)(a0 + r) * DF + f);
        short4v hv, lv;
        B2 t0 = f2b2_fast(v.x); hv[0] = t0.hi; lv[0] = t0.lo;
        B2 t1 = f2b2_fast(v.y); hv[1] = t1.hi; lv[1] = t1.lo;
        B2 t2 = f2b2_fast(v.z); hv[2] = t2.hi; lv[2] = t2.lo;
        B2 t3 = f2b2_fast(v.w); hv[3] = t3.hi; lv[3] = t3.lo;
        *(short4v*)&s_hi[r][f] = hv;
        *(short4v*)&s_lo[r][f] = lv;
    }
    __syncthreads();
    mm_tile_t<1>(acc, s_hi, s_lo, W0h, W0l, DF, 0, m0, n0, quad, lq);
    __syncthreads();
    relu_store_t<1>(acc, s_hi, s_lo, b0, m0, n0, quad, lq);
    __syncthreads();
    mm_tile_t<1>(acc, s_hi, s_lo, W1h, W1l, DF, 0, m0, n0, quad, lq);
    __syncthreads();
    relu_store_t<1>(acc, s_hi, s_lo, b1, m0, n0, quad, lq);
    __syncthreads();
    mm_tile_t<1>(acc, s_hi, s_lo, W2h, W2l, DF, 0, m0, n0, quad, lq);

    float gl[4], btl[4], bb[4];
#pragma unroll
    for (int nt = 0; nt < 4; ++nt) {
        gl[nt]  = gamma[n0 + nt * 16 + lq];
        btl[nt] = beta[n0 + nt * 16 + lq];
        bb[nt]  = b2[n0 + nt * 16 + lq];
    }
    const int half = n0 >> 6;
#pragma unroll
    for (int i = 0; i < 4; ++i) {
        float vs = 0.f, vss = 0.f;
#pragma unroll
        for (int nt = 0; nt < 4; ++nt) {
            const float v = acc[0][nt][i] + bb[nt];
            vs += v; vss += v * v;
        }
        vs  += __shfl_xor(vs, 1);  vs  += __shfl_xor(vs, 2);
        vs  += __shfl_xor(vs, 4);  vs  += __shfl_xor(vs, 8);
        vss += __shfl_xor(vss, 1); vss += __shfl_xor(vss, 2);
        vss += __shfl_xor(vss, 4); vss += __shfl_xor(vss, 8);
        if (lq == 0) {
            const int row = m0 + quad * 4 + i;
            spS[row][half] = vs;
            spSS[row][half] = vss;
        }
    }
    __syncthreads();

#pragma unroll
    for (int i = 0; i < 4; ++i) {
        const int row = m0 + quad * 4 + i;
        const int a = a0 + row;
        if (a < N) {
            const float mu  = (spS[row][0] + spS[row][1]) * (1.f / 128.f);
            const float var = (spSS[row][0] + spSS[row][1]) * (1.f / 128.f) - mu * mu;
            const float inv = rsqrtf(var + LNEPS);
#pragma unroll
            for (int nt = 0; nt < 4; ++nt) {
                const float v = acc[0][nt][i] + bb[nt];
                out[(size_t)a * DF + n0 + nt * 16 + lq] = (v - mu) * inv * gl[nt] + btl[nt];
            }
        }
    }
}

extern "C" void kernel_launch(void* const* d_in, const int* in_sizes, int n_in,
                              void* d_out, int out_size, void* d_ws, size_t ws_size,
                              hipStream_t stream)
{
    const float* x   = (const float*)d_in[0];
    const float* ea  = (const float*)d_in[1];
    const int* recv  = (const int*)d_in[2];
    const int* send  = (const int*)d_in[3];
    const float* eW0 = (const float*)d_in[5];
    const float* eb0 = (const float*)d_in[6];
    const float* eW1 = (const float*)d_in[7];
    const float* eb1 = (const float*)d_in[8];
    const float* eW2 = (const float*)d_in[9];
    const float* eb2 = (const float*)d_in[10];
    const float* eg  = (const float*)d_in[11];
    const float* ebt = (const float*)d_in[12];
    const float* nW0 = (const float*)d_in[13];
    const float* nb0 = (const float*)d_in[14];
    const float* nW1 = (const float*)d_in[15];
    const float* nb1 = (const float*)d_in[16];
    const float* nW2 = (const float*)d_in[17];
    const float* nb2 = (const float*)d_in[18];
    const float* ng  = (const float*)d_in[19];
    const float* nbt = (const float*)d_in[20];

    const int E = in_sizes[2];
    const int N = in_sizes[0] / DF;

    WConvArgs wa;
    wa.W[0] = eW0; wa.din[0] = 384;
    wa.W[1] = eW1; wa.din[1] = 128;
    wa.W[2] = eW2; wa.din[2] = 128;
    wa.W[3] = nW0; wa.din[3] = 128;
    wa.W[4] = nW1; wa.din[4] = 128;
    wa.W[5] = nW2; wa.din[5] = 128;
    wa.g = eg; wa.bt = ebt;
    wconv_all<<<513, 256, 0, stream>>>(wa);

    pq_kernel<<<(N + MTS - 1) / MTS, 256, 0, stream>>>(x, N);

    edge_kernel<<<(E + MT - 1) / MT, 256, 0, stream>>>(
        ea, recv, send, eb0, eb1, eb2, eg, ebt, E);
    node_kernel<<<(N + MTS - 1) / MTS, 256, 0, stream>>>(
        (float*)d_out, nb0, nb1, nb2, ng, nbt, N);
}

// Round 7
// 425.400 us; speedup vs baseline: 1.3720x; 1.3720x over previous
//
#include <hip/hip_runtime.h>

#define DF 128
#define MT 64          // rows per block (edge)
#define MTS 32         // rows per block (pq/node)
#define LNEPS 1e-5f
#define NATOMS 20000

typedef __attribute__((ext_vector_type(8))) short short8;
typedef __attribute__((ext_vector_type(4))) short short4v;
typedef __attribute__((ext_vector_type(4))) float float4v;

// ---- module-global scratch ----
// Weights stored FRAGMENT-CONTIGUOUS: [kblk][nb][lane][8] shorts, where
// kblk = K/32 block, nb = out-col/16 block, lane = quad*16+lq.
// value = W^T[nb*16+lq][kblk*32 + (lane>>4)*8 + e]  (bitwise same values as before,
// just reordered so a wave's B-fragment load is 64 lanes x 16 B CONTIGUOUS).
#define EW0H 0
#define EW0L (EW0H + 384*128)
#define EW1H (EW0L + 384*128)
#define EW1L (EW1H + 128*128)
#define EW2H (EW1L + 128*128)
#define EW2L (EW2H + 128*128)
#define NW0H (EW2L + 128*128)
#define NW0L (NW0H + 128*128)
#define NW1H (NW0L + 128*128)
#define NW1L (NW1H + 128*128)
#define NW2H (NW1L + 128*128)
#define NW2L (NW2H + 128*128)
#define WTOT (NW2L + 128*128)   // 262144 shorts = 512 KB

__device__ short g_w[WTOT];
__device__ float g_nodein[NATOMS * DF];   // 10.24 MB
__device__ float g_P[NATOMS * DF];        // x @ W0a (recv part)
__device__ float g_Q[NATOMS * DF];        // x @ W0b (send part)
__device__ float g_sgs[8], g_sbs[8];      // per-16-chunk sum(gamma), sum(beta) for edge LN

__device__ __forceinline__ short f2bf(float f) {
    union { float f; unsigned u; } v; v.f = f;
    unsigned r = v.u + 0x7FFFu + ((v.u >> 16) & 1u);  // RNE
    return (short)(r >> 16);
}
__device__ __forceinline__ float bf2f(short s) {
    union { unsigned u; float f; } v; v.u = ((unsigned)(unsigned short)s) << 16;
    return v.f;
}
struct B2 { short hi, lo; };
// exact-RNE split (weight convert only)
__device__ __forceinline__ B2 f2b2(float v) {
    B2 r;
    r.hi = f2bf(v);
    r.lo = f2bf(v - bf2f(r.hi));
    return r;
}
// fast split: half-up rounding, ~6 VALU
__device__ __forceinline__ B2 f2b2_fast(float v) {
    union { float f; unsigned u; } a; a.f = v;
    const unsigned hu = (a.u + 0x8000u) & 0xFFFF0000u;
    union { unsigned u; float f; } h; h.u = hu;
    const float rr = v - h.f;
    union { float f; unsigned u; } b; b.f = rr;
    B2 o;
    o.hi = (short)(hu >> 16);
    o.lo = (short)((b.u + 0x8000u) >> 16);
    return o;
}

// ---------------- weight convert: bf16 hi/lo, fragment-contiguous ----------------
struct WConvArgs {
    const float* W[6];
    int din[6];
    const float* g;    // edge LN gamma
    const float* bt;   // edge LN beta
};

__global__ void wconv_all(WConvArgs a) {
    const int b = blockIdx.x;
    if (b == 512) {   // per-chunk gamma/beta sums for the edge LN epilogue
        if (threadIdx.x < 8) {
            float sg = 0.f, sb = 0.f;
#pragma unroll
            for (int j = 0; j < 16; ++j) {
                sg += a.g[threadIdx.x * 16 + j];
                sb += a.bt[threadIdx.x * 16 + j];
            }
            g_sgs[threadIdx.x] = sg;
            g_sbs[threadIdx.x] = sb;
        }
        return;
    }
    const int baseh[6] = {EW0H, EW1H, EW2H, NW0H, NW1H, NW2H};
    const int dlo[6]   = {384*128, 128*128, 128*128, 128*128, 128*128, 128*128};
    int m, idx;
    if (b < 192) { m = 0; idx = b * 256 + threadIdx.x; }                 // eW0: 384*128
    else { m = 1 + (b - 192) / 64; idx = ((b - 192) % 64) * 256 + threadIdx.x; }
    // fragment-contiguous decomposition: idx = ((kblk*8 + nb)*64 + lane)*8 + e
    const int e    = idx & 7;
    const int lane = (idx >> 3) & 63;
    const int nb   = (idx >> 9) & 7;
    const int kblk = idx >> 12;
    const int quad = lane >> 4, lq = lane & 15;
    const int i = kblk * 32 + quad * 8 + e;   // input row
    const int o = nb * 16 + lq;               // output col
    const float w = a.W[m][(size_t)i * DF + o];
    B2 r = f2b2(w);
    g_w[baseh[m] + idx] = r.hi;
    g_w[baseh[m] + dlo[m] + idx] = r.lo;
}

// ---------------- MTWx16-row x 64-col per-wave MFMA tile, 3-pass bf16 hi/lo ----------------
// B-fragments are fragment-contiguous in g_w: off = ((kblk0+ks)*8 + nb)*512 + lane*8.
template<int MTW>
__device__ __forceinline__ void mm_tile_t(float4v (&acc)[MTW][4],
                                          const short (*hi)[136], const short (*lo)[136],
                                          const short* __restrict__ Whi,
                                          const short* __restrict__ Wlo,
                                          int kblk0, int m0, int n0, int quad, int lq)
{
    const int lane = quad * 16 + lq;
    const int base0 = ((kblk0 * 8 + (n0 >> 4)) * 64 + lane) * 8;
#pragma unroll
    for (int ks = 0; ks < 4; ++ks) {
        const int k0 = ks * 32 + quad * 8;
        short8 ah[MTW], al[MTW], bh[4], bl[4];
#pragma unroll
        for (int mt = 0; mt < MTW; ++mt) {
            const int r = m0 + mt * 16 + lq;
            ah[mt] = *(const short8*)&hi[r][k0];
            al[mt] = *(const short8*)&lo[r][k0];
        }
#pragma unroll
        for (int nt = 0; nt < 4; ++nt) {
            const int off = base0 + ks * 4096 + nt * 512;
            bh[nt] = *(const short8*)(Whi + off);
            bl[nt] = *(const short8*)(Wlo + off);
        }
#pragma unroll
        for (int mt = 0; mt < MTW; ++mt)
#pragma unroll
            for (int nt = 0; nt < 4; ++nt) {
                acc[mt][nt] = __builtin_amdgcn_mfma_f32_16x16x32_bf16(ah[mt], bh[nt], acc[mt][nt], 0, 0, 0);
                acc[mt][nt] = __builtin_amdgcn_mfma_f32_16x16x32_bf16(al[mt], bh[nt], acc[mt][nt], 0, 0, 0);
                acc[mt][nt] = __builtin_amdgcn_mfma_f32_16x16x32_bf16(ah[mt], bl[nt], acc[mt][nt], 0, 0, 0);
            }
    }
}

template<int MTW>
__device__ __forceinline__ void relu_store_t(float4v (&acc)[MTW][4],
                                             short (*hi)[136], short (*lo)[136],
                                             const float* __restrict__ bias,
                                             int m0, int n0, int quad, int lq)
{
#pragma unroll
    for (int nt = 0; nt < 4; ++nt) {
        const float bb = bias[n0 + nt * 16 + lq];
#pragma unroll
        for (int mt = 0; mt < MTW; ++mt)
#pragma unroll
            for (int i = 0; i < 4; ++i) {
                const float v = fmaxf(acc[mt][nt][i] + bb, 0.f);
                const int r = m0 + mt * 16 + quad * 4 + i;
                const int c = n0 + nt * 16 + lq;
                B2 s = f2b2_fast(v);
                hi[r][c] = s.hi;
                lo[r][c] = s.lo;
                acc[mt][nt][i] = 0.f;
            }
    }
}

// ---------------- P/Q precompute: P = x@W0a, Q = x@W0b  (MT=32 for CU fill) ----------------
__launch_bounds__(256, 4)
__global__ void pq_kernel(const float* __restrict__ x, int N)
{
    __shared__ short s_hi[MTS][136];
    __shared__ short s_lo[MTS][136];

    const int tid = threadIdx.x;
    const int wave = tid >> 6, lane = tid & 63;
    const int quad = lane >> 4, lq = lane & 15;
    const int m0 = (wave & 1) * 16, n0 = (wave >> 1) * 64;
    const int a0 = blockIdx.x * MTS;

    const short* W0h = &g_w[EW0H]; const short* W0l = &g_w[EW0L];

#pragma unroll
    for (int it = 0; it < 4; ++it) {
        const int flat = it * 1024 + tid * 4;
        const int r = flat >> 7, f = flat & 127;
        float4 v = {0.f, 0.f, 0.f, 0.f};
        if (a0 + r < N) v = *(const float4*)(x + (size_t)(a0 + r) * DF + f);
        short4v hv, lv;
        B2 t0 = f2b2_fast(v.x); hv[0] = t0.hi; lv[0] = t0.lo;
        B2 t1 = f2b2_fast(v.y); hv[1] = t1.hi; lv[1] = t1.lo;
        B2 t2 = f2b2_fast(v.z); hv[2] = t2.hi; lv[2] = t2.lo;
        B2 t3 = f2b2_fast(v.w); hv[3] = t3.hi; lv[3] = t3.lo;
        *(short4v*)&s_hi[r][f] = hv;
        *(short4v*)&s_lo[r][f] = lv;
    }
    __syncthreads();

    float4v acc[1][4] = {};
    // P: K-slice 0..127 of eW0 (kblk 0..3)
    mm_tile_t<1>(acc, s_hi, s_lo, W0h, W0l, 0, m0, n0, quad, lq);
#pragma unroll
    for (int i = 0; i < 4; ++i) {
        const int a = a0 + m0 + quad * 4 + i;
        if (a < N)
#pragma unroll
            for (int nt = 0; nt < 4; ++nt)
                g_P[(size_t)a * DF + n0 + nt * 16 + lq] = acc[0][nt][i];
#pragma unroll
        for (int nt = 0; nt < 4; ++nt) acc[0][nt][i] = 0.f;
    }
    // Q: K-slice 128..255 (kblk 4..7), staging unchanged, no barrier needed
    mm_tile_t<1>(acc, s_hi, s_lo, W0h, W0l, 4, m0, n0, quad, lq);
#pragma unroll
    for (int i = 0; i < 4; ++i) {
        const int a = a0 + m0 + quad * 4 + i;
        if (a < N)
#pragma unroll
            for (int nt = 0; nt < 4; ++nt)
                g_Q[(size_t)a * DF + n0 + nt * 16 + lq] = acc[0][nt][i];
    }
}

// ---------------- fused edge MLP + LN + chunk-sum ----------------
__launch_bounds__(256, 4)
__global__ void edge_kernel(
    const float* __restrict__ edge_attr,
    const int* __restrict__ recv, const int* __restrict__ send,
    const float* __restrict__ b0, const float* __restrict__ b1, const float* __restrict__ b2,
    const float* __restrict__ gamma, const float* __restrict__ beta,
    int E)
{
    __shared__ short s_hi[MT][136];
    __shared__ short s_lo[MT][136];
    __shared__ float spS[MT][2], spSS[MT][2];   // per-row sum / sumsq (by n0-half)
    __shared__ float cs[MT][8];                 // per-row per-chunk gamma-dot

    const int tid = threadIdx.x;
    const int wave = tid >> 6, lane = tid & 63;
    const int quad = lane >> 4, lq = lane & 15;
    const int m0 = (wave >> 1) * 32, n0 = (wave & 1) * 64;
    const int e0 = blockIdx.x * MT;

    const short* W0h = &g_w[EW0H]; const short* W0l = &g_w[EW0L];
    const short* W1h = &g_w[EW1H]; const short* W1l = &g_w[EW1L];
    const short* W2h = &g_w[EW2H]; const short* W2l = &g_w[EW2L];

    // ---- phase A0: index loads FIRST (head of the longest chain: idx -> gather) ----
    int rr[8], sr[8];
#pragma unroll
    for (int mt = 0; mt < 2; ++mt)
#pragma unroll
        for (int i = 0; i < 4; ++i) {
            const int r = m0 + mt * 16 + quad * 4 + i;
            const int e = e0 + r;
            rr[mt * 4 + i] = (e < E) ? recv[e] : 0;
            sr[mt * 4 + i] = (e < E) ? send[e] : 0;
        }

    // ---- phase A1: stream edge_attr tile into registers (flies under idx latency) ----
    const float* easrc = edge_attr + (size_t)e0 * DF;
    float4 eav[8];
#pragma unroll
    for (int it = 0; it < 8; ++it) {
        const int flat = it * 1024 + tid * 4;
        float4 z = {0.f, 0.f, 0.f, 0.f};
        eav[it] = (e0 + (flat >> 7) < E) ? *(const float4*)(easrc + flat) : z;
    }

    // ---- phase A2: per-lane PQ gather — each lane loads exactly the 32 P + 32 Q
    // dwords its acc fragments need (64 independent dword loads, no LDS round trip) ----
    float pqp[2][4][4], pqq[2][4][4];
#pragma unroll
    for (int mt = 0; mt < 2; ++mt)
#pragma unroll
        for (int i = 0; i < 4; ++i) {
            const float* Pr = g_P + (size_t)rr[mt * 4 + i] * DF + n0 + lq;
            const float* Qr = g_Q + (size_t)sr[mt * 4 + i] * DF + n0 + lq;
#pragma unroll
            for (int nt = 0; nt < 4; ++nt) {
                pqp[mt][nt][i] = Pr[nt * 16];
                pqq[mt][nt][i] = Qr[nt * 16];
            }
        }

    // ---- phase C: edge_attr -> bf16 hi/lo staging (VALU work hides gather latency) ----
#pragma unroll
    for (int it = 0; it < 8; ++it) {
        const int flat = it * 1024 + tid * 4;
        const int rw = flat >> 7, c = flat & 127;
        short4v hv, lv;
        B2 t0 = f2b2_fast(eav[it].x); hv[0] = t0.hi; lv[0] = t0.lo;
        B2 t1 = f2b2_fast(eav[it].y); hv[1] = t1.hi; lv[1] = t1.lo;
        B2 t2 = f2b2_fast(eav[it].z); hv[2] = t2.hi; lv[2] = t2.lo;
        B2 t3 = f2b2_fast(eav[it].w); hv[3] = t3.hi; lv[3] = t3.lo;
        *(short4v*)&s_hi[rw][c] = hv;
        *(short4v*)&s_lo[rw][c] = lv;
    }
    __syncthreads();

    // acc starts as the P+Q contribution; mm0 accumulates ea @ W0c on top
    float4v acc[2][4];
#pragma unroll
    for (int mt = 0; mt < 2; ++mt)
#pragma unroll
        for (int nt = 0; nt < 4; ++nt) {
            float4v t;
#pragma unroll
            for (int i = 0; i < 4; ++i)
                t[i] = pqp[mt][nt][i] + pqq[mt][nt][i];
            acc[mt][nt] = t;
        }

    mm_tile_t<2>(acc, s_hi, s_lo, W0h, W0l, 8, m0, n0, quad, lq);   // ea @ W0c: kblk 8..11
    __syncthreads();
    relu_store_t<2>(acc, s_hi, s_lo, b0, m0, n0, quad, lq);
    __syncthreads();
    mm_tile_t<2>(acc, s_hi, s_lo, W1h, W1l, 0, m0, n0, quad, lq);
    __syncthreads();
    relu_store_t<2>(acc, s_hi, s_lo, b1, m0, n0, quad, lq);
    __syncthreads();
    mm_tile_t<2>(acc, s_hi, s_lo, W2h, W2l, 0, m0, n0, quad, lq);

    // ---- LN epilogue pass 1: register-level shuffle reductions ----
    float gl[4], bb[4];
#pragma unroll
    for (int nt = 0; nt < 4; ++nt) {
        gl[nt] = gamma[n0 + nt * 16 + lq];
        bb[nt] = b2[n0 + nt * 16 + lq];
    }
    const int half = n0 >> 6;
#pragma unroll
    for (int mt = 0; mt < 2; ++mt)
#pragma unroll
        for (int i = 0; i < 4; ++i) {
            float v[4], vs = 0.f, vss = 0.f;
#pragma unroll
            for (int nt = 0; nt < 4; ++nt) {
                v[nt] = acc[mt][nt][i] + bb[nt];
                vs += v[nt]; vss += v[nt] * v[nt];
            }
            vs  += __shfl_xor(vs, 1);  vs  += __shfl_xor(vs, 2);
            vs  += __shfl_xor(vs, 4);  vs  += __shfl_xor(vs, 8);
            vss += __shfl_xor(vss, 1); vss += __shfl_xor(vss, 2);
            vss += __shfl_xor(vss, 4); vss += __shfl_xor(vss, 8);
            float cd[4];
#pragma unroll
            for (int nt = 0; nt < 4; ++nt) {
                float c = v[nt] * gl[nt];
                c += __shfl_xor(c, 1); c += __shfl_xor(c, 2);
                c += __shfl_xor(c, 4); c += __shfl_xor(c, 8);
                cd[nt] = c;
            }
            if (lq == 0) {
                const int row = m0 + mt * 16 + quad * 4 + i;
                spS[row][half] = vs;
                spSS[row][half] = vss;
#pragma unroll
                for (int nt = 0; nt < 4; ++nt)
                    cs[row][(n0 >> 4) + nt] = cd[nt];
            }
        }
    __syncthreads();

    // ---- pass 2: finalize LN-transformed chunk sums, write node_in ----
    for (int cell = tid; cell < MT * 8; cell += 256) {
        const int rw = cell >> 3, c = cell & 7;
        const float mu  = (spS[rw][0] + spS[rw][1]) * (1.f / 128.f);
        const float var = (spSS[rw][0] + spSS[rw][1]) * (1.f / 128.f) - mu * mu;
        const float inv = rsqrtf(var + LNEPS);
        const int ee = e0 + rw;
        if (ee < E)
            g_nodein[(size_t)ee * 8 + c] = inv * (cs[rw][c] - mu * g_sgs[c]) + g_sbs[c];
    }
}

// ---------------- fused node MLP + LN: g_nodein -> d_out  (MT=32 for CU fill) ----------------
__launch_bounds__(256, 4)
__global__ void node_kernel(
    float* __restrict__ out,
    const float* __restrict__ b0, const float* __restrict__ b1, const float* __restrict__ b2,
    const float* __restrict__ gamma, const float* __restrict__ beta,
    int N)
{
    __shared__ short s_hi[MTS][136];
    __shared__ short s_lo[MTS][136];
    __shared__ float spS[MTS][2], spSS[MTS][2];

    const int tid = threadIdx.x;
    const int wave = tid >> 6, lane = tid & 63;
    const int quad = lane >> 4, lq = lane & 15;
    const int m0 = (wave & 1) * 16, n0 = (wave >> 1) * 64;
    const int a0 = blockIdx.x * MTS;

    const short* W0h = &g_w[NW0H]; const short* W0l = &g_w[NW0L];
    const short* W1h = &g_w[NW1H]; const short* W1l = &g_w[NW1L];
    const short* W2h = &g_w[NW2H]; const short* W2l = &g_w[NW2L];

    float4v acc[1][4] = {};

#pragma unroll
    for (int it = 0; it < 4; ++it) {
        const int flat = it * 1024 + tid * 4;
        const int r = flat >> 7, f = flat & 127;
        float4 v = {0.f, 0.f, 0.f, 0.f};
        if (a0 + r < N) v = *(const float4*)(g_nodein + (size_t)(a0 + r) * DF + f);
        short4v hv, lv;
        B2 t0 = f2b2_fast(v.x); hv[0] = t0.hi; lv[0] = t0.lo;
        B2 t1 = f2b2_fast(v.y); hv[1] = t1.hi; lv[1] = t1.lo;
        B2 t2 = f2b2_fast(v.z); hv[2] = t2.hi; lv[2] = t2.lo;
        B2 t3 = f2b2_fast(v.w); hv[3] = t3.hi; lv[3] = t3.lo;
        *(short4v*)&s_hi[r][f] = hv;
        *(short4v*)&s_lo[r][f] = lv;
    }
    __syncthreads();
    mm_tile_t<1>(acc, s_hi, s_lo, W0h, W0l, 0, m0, n0, quad, lq);
    __syncthreads();
    relu_store_t<1>(acc, s_hi, s_lo, b0, m0, n0, quad, lq);
    __syncthreads();
    mm_tile_t<1>(acc, s_hi, s_lo, W1h, W1l, 0, m0, n0, quad, lq);
    __syncthreads();
    relu_store_t<1>(acc, s_hi, s_lo, b1, m0, n0, quad, lq);
    __syncthreads();
    mm_tile_t<1>(acc, s_hi, s_lo, W2h, W2l, 0, m0, n0, quad, lq);

    float gl[4], btl[4], bb[4];
#pragma unroll
    for (int nt = 0; nt < 4; ++nt) {
        gl[nt]  = gamma[n0 + nt * 16 + lq];
        btl[nt] = beta[n0 + nt * 16 + lq];
        bb[nt]  = b2[n0 + nt * 16 + lq];
    }
    const int half = n0 >> 6;
#pragma unroll
    for (int i = 0; i < 4; ++i) {
        float vs = 0.f, vss = 0.f;
#pragma unroll
        for (int nt = 0; nt < 4; ++nt) {
            const float v = acc[0][nt][i] + bb[nt];
            vs += v; vss += v * v;
        }
        vs  += __shfl_xor(vs, 1);  vs  += __shfl_xor(vs, 2);
        vs  += __shfl_xor(vs, 4);  vs  += __shfl_xor(vs, 8);
        vss += __shfl_xor(vss, 1); vss += __shfl_xor(vss, 2);
        vss += __shfl_xor(vss, 4); vss += __shfl_xor(vss, 8);
        if (lq == 0) {
            const int row = m0 + quad * 4 + i;
            spS[row][half] = vs;
            spSS[row][half] = vss;
        }
    }
    __syncthreads();

#pragma unroll
    for (int i = 0; i < 4; ++i) {
        const int row = m0 + quad * 4 + i;
        const int a = a0 + row;
        if (a < N) {
            const float mu  = (spS[row][0] + spS[row][1]) * (1.f / 128.f);
            const float var = (spSS[row][0] + spSS[row][1]) * (1.f / 128.f) - mu * mu;
            const float inv = rsqrtf(var + LNEPS);
#pragma unroll
            for (int nt = 0; nt < 4; ++nt) {
                const float v = acc[0][nt][i] + bb[nt];
                out[(size_t)a * DF + n0 + nt * 16 + lq] = (v - mu) * inv * gl[nt] + btl[nt];
            }
        }
    }
}

extern "C" void kernel_launch(void* const* d_in, const int* in_sizes, int n_in,
                              void* d_out, int out_size, void* d_ws, size_t ws_size,
                              hipStream_t stream)
{
    const float* x   = (const float*)d_in[0];
    const float* ea  = (const float*)d_in[1];
    const int* recv  = (const int*)d_in[2];
    const int* send  = (const int*)d_in[3];
    const float* eW0 = (const float*)d_in[5];
    const float* eb0 = (const float*)d_in[6];
    const float* eW1 = (const float*)d_in[7];
    const float* eb1 = (const float*)d_in[8];
    const float* eW2 = (const float*)d_in[9];
    const float* eb2 = (const float*)d_in[10];
    const float* eg  = (const float*)d_in[11];
    const float* ebt = (const float*)d_in[12];
    const float* nW0 = (const float*)d_in[13];
    const float* nb0 = (const float*)d_in[14];
    const float* nW1 = (const float*)d_in[15];
    const float* nb1 = (const float*)d_in[16];
    const float* nW2 = (const float*)d_in[17];
    const float* nb2 = (const float*)d_in[18];
    const float* ng  = (const float*)d_in[19];
    const float* nbt = (const float*)d_in[20];

    const int E = in_sizes[2];
    const int N = in_sizes[0] / DF;

    WConvArgs wa;
    wa.W[0] = eW0; wa.din[0] = 384;
    wa.W[1] = eW1; wa.din[1] = 128;
    wa.W[2] = eW2; wa.din[2] = 128;
    wa.W[3] = nW0; wa.din[3] = 128;
    wa.W[4] = nW1; wa.din[4] = 128;
    wa.W[5] = nW2; wa.din[5] = 128;
    wa.g = eg; wa.bt = ebt;
    wconv_all<<<513, 256, 0, stream>>>(wa);

    pq_kernel<<<(N + MTS - 1) / MTS, 256, 0, stream>>>(x, N);

    edge_kernel<<<(E + MT - 1) / MT, 256, 0, stream>>>(
        ea, recv, send, eb0, eb1, eb2, eg, ebt, E);
    node_kernel<<<(N + MTS - 1) / MTS, 256, 0, stream>>>(
        (float*)d_out, nb0, nb1, nb2, ng, nbt, N);
}